// Round 1
// baseline (1330.871 us; speedup 1.0000x reference)
//
#include <hip/hip_runtime.h>
#include <hip/hip_bf16.h>

typedef unsigned int u32;
typedef unsigned short u16;
typedef unsigned char u8;

// Weight layout inside d_ws (float elements), after 64-byte flag header:
//   w1[48*64], b1[64], w2[64*32], b2[32], w3[32*16], b3[16]
#define OFF_W1 0
#define OFF_B1 3072
#define OFF_W2 3136
#define OFF_B2 5184
#define OFF_W3 5216
#define OFF_B3 5728
#define W_TOTAL 5744

// ---------------------------------------------------------------------------
// Probe: decide (a) are float inputs f32 or bf16?  (b) mask element width.
// If w1 (N(0,0.144) values) is really f32, its low 16-bit halves are mantissa
// garbage: ~25% of odd halves have exponent >= 0xC0 (|v| >= 2^65). Real bf16
// data never does. Mask: u8 bools give words with >=2 one-bytes; bf16 bools
// give 0x3F803F80 / 0x00003F80 words; int32/f32 bools are width 4 and both
// reduce to "word != 0".
// ---------------------------------------------------------------------------
__global__ void probe_kernel(const u16* __restrict__ w1h,
                             const u32* __restrict__ maskw,
                             u32* __restrict__ flags) {
  __shared__ int sg, su8, sbf;
  if (threadIdx.x == 0) { sg = 0; su8 = 0; sbf = 0; }
  __syncthreads();
  int g = 0;
#pragma unroll
  for (int i = 0; i < 8; ++i) {
    u16 h = w1h[threadIdx.x * 8 + i];   // first 2048 halves = 4KB (safe: w1 >= 6KB)
    int e = (h >> 7) & 0xFF;
    if (e >= 0xC0) g++;
  }
  if (g) atomicAdd(&sg, g);
  u32 w = maskw[threadIdx.x];           // first 1KB of mask (safe: >= 1MB)
  bool bytes01 = ((w & 0xFEFEFEFEu) == 0u);
  int bsum = (int)(w & 1u) + (int)((w >> 8) & 1u) +
             (int)((w >> 16) & 1u) + (int)((w >> 24) & 1u);
  if (bytes01 && bsum >= 2) atomicAdd(&su8, 1);
  if (w == 0x3F803F80u || w == 0x00003F80u) atomicAdd(&sbf, 1);
  __syncthreads();
  if (threadIdx.x == 0) {
    flags[0] = (sg == 0) ? 1u : 0u;                      // 1 = inputs are bf16
    flags[1] = (su8 > 0) ? 1u : ((sbf > 0) ? 2u : 4u);   // mask element bytes
  }
}

// ---------------------------------------------------------------------------
// Normalize all weights/biases to f32 in workspace (23KB), either dtype.
// ---------------------------------------------------------------------------
__global__ void prep_weights(const void* __restrict__ w1, const void* __restrict__ b1,
                             const void* __restrict__ w2, const void* __restrict__ b2,
                             const void* __restrict__ w3, const void* __restrict__ b3,
                             const u32* __restrict__ flags, float* __restrict__ W) {
  int i = blockIdx.x * 256 + threadIdx.x;
  if (i >= W_TOTAL) return;
  const void* src; int off;
  if (i < OFF_B1)      { src = w1; off = i; }
  else if (i < OFF_W2) { src = b1; off = i - OFF_B1; }
  else if (i < OFF_B2) { src = w2; off = i - OFF_W2; }
  else if (i < OFF_W3) { src = b2; off = i - OFF_B2; }
  else if (i < OFF_B3) { src = w3; off = i - OFF_W3; }
  else                 { src = b3; off = i - OFF_B3; }
  float v;
  if (flags[0]) v = __uint_as_float(((u32)((const u16*)src)[off]) << 16);
  else          v = ((const float*)src)[off];
  W[i] = v;
}

// ---------------------------------------------------------------------------
// Main kernel helpers
// ---------------------------------------------------------------------------
__device__ __forceinline__ float bf2f(u16 h) {
  return __uint_as_float(((u32)h) << 16);
}
__device__ __forceinline__ u16 f2bf(float f) {  // round-nearest-even
  u32 u = __float_as_uint(f);
  return (u16)((u + 0x7FFFu + ((u >> 16) & 1u)) >> 16);
}

template <bool BF16>
__device__ __forceinline__ float4 load4x(const void* __restrict__ xv, int e) {
  if (BF16) {
    ushort4 u = *(const ushort4*)((const u16*)xv + e);   // 8B aligned (e % 4 == 0)
    return make_float4(bf2f(u.x), bf2f(u.y), bf2f(u.z), bf2f(u.w));
  } else {
    return *(const float4*)((const float*)xv + e);
  }
}

// acc[d] += s * wrow[4d .. 4d+3], d in [0, ND)
template <int ND>
__device__ __forceinline__ void accrow(float4* acc, float s, const float* __restrict__ wr) {
#pragma unroll
  for (int d = 0; d < ND; ++d) {
    float4 w4 = *(const float4*)(wr + 4 * d);   // wave-uniform address -> s_load
    acc[d].x = fmaf(s, w4.x, acc[d].x);
    acc[d].y = fmaf(s, w4.y, acc[d].y);
    acc[d].z = fmaf(s, w4.z, acc[d].z);
    acc[d].w = fmaf(s, w4.w, acc[d].w);
  }
}

__device__ __forceinline__ float fast_tanh(float x) {
  // tanh(x) = 1 - 2/(exp(2x)+1); exp->inf gives 1, exp->0 gives -1 (no NaN)
  float e = __expf(2.0f * x);
  float r = __builtin_amdgcn_rcpf(e + 1.0f);
  return fmaf(-2.0f, r, 1.0f);
}

template <bool BF16>
__device__ __forceinline__ void nca_body(const void* __restrict__ xv,
                                         const float* __restrict__ W,
                                         const void* __restrict__ maskv, int mw,
                                         void* __restrict__ outv) {
  const int p    = blockIdx.x * 256 + threadIdx.x;  // pixel index; 1 block = 1 row
  const int wpos = p & 255;
  const int hpos = (p >> 8) & 255;
  const int img  = p >> 16;

  const bool rv0 = hpos > 0, rv2 = hpos < 255;
  const bool cv0 = wpos > 0, cv2 = wpos < 255;

  int rowb0 = ((img << 8) + hpos - 1) << 8;   // pixel index of (img, hpos-1, 0)
  int rowb1 = rowb0 + 256;
  int rowb2 = rowb1 + 256;

  // ---- layer 1 accumulators, init with b1 -------------------------------
  float4 acc1[16];
#pragma unroll
  for (int d = 0; d < 16; ++d) acc1[d] = *(const float4*)(W + OFF_B1 + 4 * d);

  // ---- perceive + accumulate into h1 (y never materialized) -------------
#pragma unroll
  for (int cg = 0; cg < 4; ++cg) {
    float nn[3][3][4];
#pragma unroll
    for (int i = 0; i < 3; ++i) {
      const bool rvalid = (i == 0) ? rv0 : ((i == 2) ? rv2 : true);
      const int rb = (i == 0) ? rowb0 : ((i == 1) ? rowb1 : rowb2);
#pragma unroll
      for (int j = 0; j < 3; ++j) {
        const bool cvalid = (j == 0) ? cv0 : ((j == 2) ? cv2 : true);
        float4 t;
        if (rvalid && cvalid) {
          int e = (rb + wpos + j - 1) * 16 + cg * 4;
          t = load4x<BF16>(xv, e);
        } else {
          t = make_float4(0.f, 0.f, 0.f, 0.f);
        }
        nn[i][j][0] = t.x; nn[i][j][1] = t.y; nn[i][j][2] = t.z; nn[i][j][3] = t.w;
      }
    }
#pragma unroll
    for (int q = 0; q < 4; ++q) {
      float iv = nn[1][1][q];
      float gx = ((nn[0][2][q] - nn[0][0][q]) + 2.0f * (nn[1][2][q] - nn[1][0][q]) +
                  (nn[2][2][q] - nn[2][0][q])) * 0.125f;
      float gy = ((nn[2][0][q] - nn[0][0][q]) + 2.0f * (nn[2][1][q] - nn[0][1][q]) +
                  (nn[2][2][q] - nn[0][2][q])) * 0.125f;
      const int c = cg * 4 + q;
      accrow<16>(acc1, iv, W + OFF_W1 + (3 * c + 0) * 64);
      accrow<16>(acc1, gx, W + OFF_W1 + (3 * c + 1) * 64);
      accrow<16>(acc1, gy, W + OFF_W1 + (3 * c + 2) * 64);
    }
  }

  // ---- tanh -> h1 --------------------------------------------------------
  float h1[64];
#pragma unroll
  for (int d = 0; d < 16; ++d) {
    h1[4 * d + 0] = fast_tanh(acc1[d].x);
    h1[4 * d + 1] = fast_tanh(acc1[d].y);
    h1[4 * d + 2] = fast_tanh(acc1[d].z);
    h1[4 * d + 3] = fast_tanh(acc1[d].w);
  }

  // ---- layer 2: 64 -> 32 -------------------------------------------------
  float4 acc2[8];
#pragma unroll
  for (int d = 0; d < 8; ++d) acc2[d] = *(const float4*)(W + OFF_B2 + 4 * d);
#pragma unroll
  for (int c = 0; c < 64; ++c) accrow<8>(acc2, h1[c], W + OFF_W2 + c * 32);

  float h2[32];
#pragma unroll
  for (int d = 0; d < 8; ++d) {
    h2[4 * d + 0] = fast_tanh(acc2[d].x);
    h2[4 * d + 1] = fast_tanh(acc2[d].y);
    h2[4 * d + 2] = fast_tanh(acc2[d].z);
    h2[4 * d + 3] = fast_tanh(acc2[d].w);
  }

  // ---- layer 3: 32 -> 16 (no tanh) ---------------------------------------
  float4 acc3[4];
#pragma unroll
  for (int d = 0; d < 4; ++d) acc3[d] = *(const float4*)(W + OFF_B3 + 4 * d);
#pragma unroll
  for (int c = 0; c < 32; ++c) accrow<4>(acc3, h2[c], W + OFF_W3 + c * 16);

  // ---- mask --------------------------------------------------------------
  bool ms;
  if (mw == 1)      ms = ((const u8*)maskv)[p] != 0;
  else if (mw == 2) ms = ((const u16*)maskv)[p] != 0;
  else              ms = ((const u32*)maskv)[p] != 0;
  const float mf = ms ? 1.0f : 0.0f;

  // ---- out = x + dx * mask ----------------------------------------------
  float o[16];
#pragma unroll
  for (int g = 0; g < 4; ++g) {
    float4 xc = load4x<BF16>(xv, p * 16 + 4 * g);
    o[4 * g + 0] = fmaf(acc3[g].x, mf, xc.x);
    o[4 * g + 1] = fmaf(acc3[g].y, mf, xc.y);
    o[4 * g + 2] = fmaf(acc3[g].z, mf, xc.z);
    o[4 * g + 3] = fmaf(acc3[g].w, mf, xc.w);
  }

  if (BF16) {
    u32 pk[8];
#pragma unroll
    for (int k = 0; k < 8; ++k)
      pk[k] = (u32)f2bf(o[2 * k]) | ((u32)f2bf(o[2 * k + 1]) << 16);
    uint4* dst = (uint4*)((u16*)outv + p * 16);
    dst[0] = make_uint4(pk[0], pk[1], pk[2], pk[3]);
    dst[1] = make_uint4(pk[4], pk[5], pk[6], pk[7]);
  } else {
    float4* dst = (float4*)((float*)outv + p * 16);
    dst[0] = make_float4(o[0], o[1], o[2], o[3]);
    dst[1] = make_float4(o[4], o[5], o[6], o[7]);
    dst[2] = make_float4(o[8], o[9], o[10], o[11]);
    dst[3] = make_float4(o[12], o[13], o[14], o[15]);
  }
}

__global__ __launch_bounds__(256) void nca_main(const void* __restrict__ xv,
                                                const float* __restrict__ W,
                                                const void* __restrict__ maskv,
                                                const u32* __restrict__ flags,
                                                void* __restrict__ outv) {
  const bool isbf = flags[0] != 0;   // wave-uniform branch
  const int mw = (int)flags[1];
  if (isbf) nca_body<true>(xv, W, maskv, mw, outv);
  else      nca_body<false>(xv, W, maskv, mw, outv);
}

// ---------------------------------------------------------------------------
extern "C" void kernel_launch(void* const* d_in, const int* in_sizes, int n_in,
                              void* d_out, int out_size, void* d_ws, size_t ws_size,
                              hipStream_t stream) {
  // d_in: 0=x, 1=w1, 2=b1, 3=w2, 4=b2, 5=w3, 6=b3, 7=update_mask
  u32* flags = (u32*)d_ws;
  float* W = (float*)((char*)d_ws + 64);

  probe_kernel<<<1, 256, 0, stream>>>((const u16*)d_in[1], (const u32*)d_in[7], flags);

  const int wblocks = (W_TOTAL + 255) / 256;
  prep_weights<<<wblocks, 256, 0, stream>>>(d_in[1], d_in[2], d_in[3], d_in[4],
                                            d_in[5], d_in[6], flags, W);

  const int pixels = in_sizes[7];            // B*H*W = 1048576
  const int blocks = (pixels + 255) / 256;   // one 256-wide row per block
  nca_main<<<blocks, 256, 0, stream>>>(d_in[0], W, d_in[7], flags, d_out);
}

// Round 2
// 270.722 us; speedup vs baseline: 4.9160x; 4.9160x over previous
//
#include <hip/hip_runtime.h>
#include <hip/hip_bf16.h>

typedef unsigned int u32;
typedef unsigned short u16;
typedef unsigned char u8;

typedef float f32x16 __attribute__((ext_vector_type(16)));
typedef short bf16x8 __attribute__((ext_vector_type(8)));

// ---- workspace layout (bytes after 64B flag header) ------------------------
// WT1p[64ch][64k]  bf16 : k 0..47 = w1^T, k48 = b1, k49..63 = 0        (8192B)
// WT2p[32ch][80k]  bf16 : k 0..63 = w2^T, k64 = b2, k65..79 = 0        (5120B)
// WT3p[32ch][32k]  bf16 : ch 0..15 = w3^T, ch 16..31 = 0               (2048B)
// B3[16] f32                                                            (64B)
#define OFF_WT1 0
#define OFF_WT2 8192
#define OFF_WT3 13312
#define OFF_B3  15360
#define PREP_N  (4096 + 2560 + 1024 + 16)

// ---------------------------------------------------------------------------
// Probe (unchanged from R1 — verified working): flags[0]=1 if inputs bf16,
// flags[1] = mask element width in bytes (1/2/4).
// ---------------------------------------------------------------------------
__global__ void probe_kernel(const u16* __restrict__ w1h,
                             const u32* __restrict__ maskw,
                             u32* __restrict__ flags) {
  __shared__ int sg, su8, sbf;
  if (threadIdx.x == 0) { sg = 0; su8 = 0; sbf = 0; }
  __syncthreads();
  int g = 0;
#pragma unroll
  for (int i = 0; i < 8; ++i) {
    u16 h = w1h[threadIdx.x * 8 + i];
    int e = (h >> 7) & 0xFF;
    if (e >= 0xC0) g++;
  }
  if (g) atomicAdd(&sg, g);
  u32 w = maskw[threadIdx.x];
  bool bytes01 = ((w & 0xFEFEFEFEu) == 0u);
  int bsum = (int)(w & 1u) + (int)((w >> 8) & 1u) +
             (int)((w >> 16) & 1u) + (int)((w >> 24) & 1u);
  if (bytes01 && bsum >= 2) atomicAdd(&su8, 1);
  if (w == 0x3F803F80u || w == 0x00003F80u) atomicAdd(&sbf, 1);
  __syncthreads();
  if (threadIdx.x == 0) {
    flags[0] = (sg == 0) ? 1u : 0u;
    flags[1] = (su8 > 0) ? 1u : ((sbf > 0) ? 2u : 4u);
  }
}

__device__ __forceinline__ float bf2f(u16 h) {
  return __uint_as_float(((u32)h) << 16);
}
__device__ __forceinline__ u16 f2bf(float f) {  // RNE
  u32 u = __float_as_uint(f);
  return (u16)((u + 0x7FFFu + ((u >> 16) & 1u)) >> 16);
}
__device__ __forceinline__ u32 pkbf(float a, float b) {  // a->low, b->high
  __hip_bfloat162 t = __float22bfloat162_rn(make_float2(a, b));
  union { __hip_bfloat162 h; u32 u; } c; c.h = t; return c.u;
}
__device__ __forceinline__ float rdv(const void* s, int i, bool bf) {
  return bf ? bf2f(((const u16*)s)[i]) : ((const float*)s)[i];
}

// ---------------------------------------------------------------------------
// Weight prep: build transposed, K-augmented bf16 weight blocks + f32 b3.
// ---------------------------------------------------------------------------
__global__ void prep_weights(const void* __restrict__ w1, const void* __restrict__ b1,
                             const void* __restrict__ w2, const void* __restrict__ b2,
                             const void* __restrict__ w3, const void* __restrict__ b3,
                             const u32* __restrict__ flags, u8* __restrict__ Wb) {
  int i = blockIdx.x * 256 + threadIdx.x;
  if (i >= PREP_N) return;
  const bool bf = flags[0] != 0;
  if (i < 4096) {                       // WT1p: i = n*64 + k
    int n = i >> 6, k = i & 63;
    float v = (k < 48) ? rdv(w1, k * 64 + n, bf)
                       : ((k == 48) ? rdv(b1, n, bf) : 0.0f);
    ((u16*)(Wb + OFF_WT1))[i] = f2bf(v);
  } else if (i < 4096 + 2560) {         // WT2p: j = n*80 + k
    int j = i - 4096, n = j / 80, k = j - n * 80;
    float v = (k < 64) ? rdv(w2, k * 32 + n, bf)
                       : ((k == 64) ? rdv(b2, n, bf) : 0.0f);
    ((u16*)(Wb + OFF_WT2))[j] = f2bf(v);
  } else if (i < 4096 + 2560 + 1024) {  // WT3p: j = n*32 + k
    int j = i - (4096 + 2560), n = j >> 5, k = j & 31;
    float v = (n < 16) ? rdv(w3, k * 16 + n, bf) : 0.0f;
    ((u16*)(Wb + OFF_WT3))[j] = f2bf(v);
  } else {                              // B3 f32
    int j = i - (4096 + 2560 + 1024);
    ((float*)(Wb + OFF_B3))[j] = rdv(b3, j, bf);
  }
}

// ---------------------------------------------------------------------------
// Main kernel
// ---------------------------------------------------------------------------
__device__ __forceinline__ float fast_tanh(float x) {
  float e = __expf(2.0f * x);
  float r = __builtin_amdgcn_rcpf(e + 1.0f);
  return fmaf(-2.0f, r, 1.0f);
}

template <bool BF16>
__device__ __forceinline__ float4 load4x(const void* __restrict__ xv, int e) {
  if (BF16) {
    ushort4 u = *(const ushort4*)((const u16*)xv + e);
    return make_float4(bf2f(u.x), bf2f(u.y), bf2f(u.z), bf2f(u.w));
  } else {
    return *(const float4*)((const float*)xv + e);
  }
}

// perceive: fill f[48] = [c_I, c_gx, c_gy]*16 for pixel p
template <bool BF16>
__device__ __forceinline__ void perceive48(const void* __restrict__ xv, int p, float* f) {
  const int wpos = p & 255;
  const int hpos = (p >> 8) & 255;
  const int img  = p >> 16;
  const bool rv0 = hpos > 0, rv2 = hpos < 255;
  const bool cv0 = wpos > 0, cv2 = wpos < 255;
  int rowb0 = ((img << 8) + hpos - 1) << 8;
  int rowb1 = rowb0 + 256, rowb2 = rowb1 + 256;
#pragma unroll
  for (int cg = 0; cg < 4; ++cg) {
    float nn[3][3][4];
#pragma unroll
    for (int i = 0; i < 3; ++i) {
      const bool rvalid = (i == 0) ? rv0 : ((i == 2) ? rv2 : true);
      const int rb = (i == 0) ? rowb0 : ((i == 1) ? rowb1 : rowb2);
#pragma unroll
      for (int j = 0; j < 3; ++j) {
        const bool cvalid = (j == 0) ? cv0 : ((j == 2) ? cv2 : true);
        float4 t;
        if (rvalid && cvalid) t = load4x<BF16>(xv, (rb + wpos + j - 1) * 16 + cg * 4);
        else                  t = make_float4(0.f, 0.f, 0.f, 0.f);
        nn[i][j][0] = t.x; nn[i][j][1] = t.y; nn[i][j][2] = t.z; nn[i][j][3] = t.w;
      }
    }
#pragma unroll
    for (int q = 0; q < 4; ++q) {
      float iv = nn[1][1][q];
      float gx = ((nn[0][2][q] - nn[0][0][q]) + 2.0f * (nn[1][2][q] - nn[1][0][q]) +
                  (nn[2][2][q] - nn[2][0][q])) * 0.125f;
      float gy = ((nn[2][0][q] - nn[0][0][q]) + 2.0f * (nn[2][1][q] - nn[0][1][q]) +
                  (nn[2][2][q] - nn[0][2][q])) * 0.125f;
      const int c = cg * 4 + q;
      f[3 * c + 0] = iv; f[3 * c + 1] = gx; f[3 * c + 2] = gy;
    }
  }
}

union U4 { uint4 q; u32 u[4]; bf16x8 h; };

__device__ __forceinline__ void wave_lds_fence() {
  __builtin_amdgcn_wave_barrier();
  __asm__ __volatile__("s_waitcnt lgkmcnt(0)" ::: "memory");
  __builtin_amdgcn_wave_barrier();
}

#define MFMA(a, b, c) __builtin_amdgcn_mfma_f32_32x32x16_bf16((a), (b), (c), 0, 0, 0)

template <bool BF16>
__device__ __forceinline__ void nca_body(const void* __restrict__ xv,
                                         const u8* __restrict__ Wb,
                                         const void* __restrict__ maskv, int mw,
                                         void* __restrict__ outv,
                                         u8* __restrict__ smem) {
  const int tid = threadIdx.x;
  const int l   = tid & 63;
  const int wid = tid >> 6;
  const int l31 = l & 31;
  const int hi  = l >> 5;                       // 0/1 half-wave
  const int p   = blockIdx.x * 256 + tid;       // this lane's perceive pixel
  u8* Y = smem + wid * 9216;                    // wave-private [64px][72 bf16]

  // ---- preload all weight A-fragments (persistent registers) -------------
  bf16x8 A1[2][4], A2[5], A3[2];
#pragma unroll
  for (int mt = 0; mt < 2; ++mt)
#pragma unroll
    for (int s = 0; s < 4; ++s) {
      U4 t; t.q = *(const uint4*)(Wb + OFF_WT1 + (mt * 32 + l31) * 128 + s * 32 + hi * 16);
      A1[mt][s] = t.h;
    }
#pragma unroll
  for (int s = 0; s < 5; ++s) {
    U4 t; t.q = *(const uint4*)(Wb + OFF_WT2 + l31 * 160 + s * 32 + hi * 16);
    A2[s] = t.h;
  }
#pragma unroll
  for (int s = 0; s < 2; ++s) {
    U4 t; t.q = *(const uint4*)(Wb + OFF_WT3 + l31 * 64 + s * 32 + hi * 16);
    A3[s] = t.h;
  }
  const float* B3f = (const float*)(Wb + OFF_B3);
  float4 b3a = *(const float4*)(B3f + 4 * hi);       // ch 4hi..4hi+3
  float4 b3b = *(const float4*)(B3f + 8 + 4 * hi);   // ch 8+4hi..11+4hi

  // ---- perceive -> Y in LDS (bf16, K-augmented: f48=1, f49..63=0) ---------
  {
    float f[48];
    perceive48<BF16>(xv, p, f);
    u32 yw[32];
#pragma unroll
    for (int t = 0; t < 24; ++t) yw[t] = pkbf(f[2 * t], f[2 * t + 1]);
    yw[24] = pkbf(1.0f, 0.0f);
#pragma unroll
    for (int t = 25; t < 32; ++t) yw[t] = 0u;
    uint4* dst = (uint4*)(Y + l * 144);
#pragma unroll
    for (int c = 0; c < 8; ++c) dst[c] = make_uint4(yw[4*c], yw[4*c+1], yw[4*c+2], yw[4*c+3]);
  }
  wave_lds_fence();

  // ---- per 32-pixel tile ---------------------------------------------------
#pragma unroll
  for (int pt = 0; pt < 2; ++pt) {
    const int lpx = pt * 32 + l31;            // wave-local pixel of this lane's col
    // Y B-fragments (4 K-steps of 16)
    bf16x8 Yf[4];
#pragma unroll
    for (int s = 0; s < 4; ++s) {
      U4 t; t.q = *(const uint4*)(Y + lpx * 144 + s * 32 + hi * 16);
      Yf[s] = t.h;
    }
    // ---- layer 1: T1 = W1^T Y^T  (64 ch = 2 M-tiles) ----------------------
    f32x16 c0 = {0,0,0,0,0,0,0,0,0,0,0,0,0,0,0,0};
    f32x16 c1 = {0,0,0,0,0,0,0,0,0,0,0,0,0,0,0,0};
#pragma unroll
    for (int s = 0; s < 4; ++s) {
      c0 = MFMA(A1[0][s], Yf[s], c0);
      c1 = MFMA(A1[1][s], Yf[s], c1);
    }
    // tanh + pack pairs: o1[mt*8 + g*2 + pp] = (ch 32mt+8g+4hi+2pp, +1)
    int o1[16];
#pragma unroll
    for (int g = 0; g < 4; ++g)
#pragma unroll
      for (int pp = 0; pp < 2; ++pp) {
        o1[g * 2 + pp]     = pkbf(fast_tanh(c0[g * 4 + 2 * pp]), fast_tanh(c0[g * 4 + 2 * pp + 1]));
        o1[8 + g * 2 + pp] = pkbf(fast_tanh(c1[g * 4 + 2 * pp]), fast_tanh(c1[g * 4 + 2 * pp + 1]));
      }
    int p1[16];
#pragma unroll
    for (int i = 0; i < 16; ++i) p1[i] = __shfl_xor(o1[i], 32, 64);

    // ---- layer 2: 5 K-steps (last = bias row) -----------------------------
    f32x16 c2 = {0,0,0,0,0,0,0,0,0,0,0,0,0,0,0,0};
#pragma unroll
    for (int s = 0; s < 4; ++s) {
      U4 bf;
      const int mt8 = (s >> 1) * 8;
      const int g0 = ((2 * s) & 3) * 2, g1 = ((2 * s + 1) & 3) * 2;
#pragma unroll
      for (int q = 0; q < 4; ++q) {
        int vA = (q < 2) ? o1[mt8 + g0 + (q & 1)] : p1[mt8 + g0 + (q & 1)];
        int vB = (q < 2) ? p1[mt8 + g1 + (q & 1)] : o1[mt8 + g1 + (q & 1)];
        bf.u[q] = hi ? (u32)vB : (u32)vA;
      }
      c2 = MFMA(A2[s], bf.h, c2);
    }
    {
      U4 bb; bb.u[0] = hi ? 0u : 0x00003F80u; bb.u[1] = 0; bb.u[2] = 0; bb.u[3] = 0;
      c2 = MFMA(A2[4], bb.h, c2);
    }
    int o2[8];
#pragma unroll
    for (int g = 0; g < 4; ++g)
#pragma unroll
      for (int pp = 0; pp < 2; ++pp)
        o2[g * 2 + pp] = pkbf(fast_tanh(c2[g * 4 + 2 * pp]), fast_tanh(c2[g * 4 + 2 * pp + 1]));
    int p2[8];
#pragma unroll
    for (int i = 0; i < 8; ++i) p2[i] = __shfl_xor(o2[i], 32, 64);

    // ---- layer 3: 2 K-steps, M half-wasted (ch3 0..15 valid) --------------
    f32x16 c3 = {0,0,0,0,0,0,0,0,0,0,0,0,0,0,0,0};
#pragma unroll
    for (int s = 0; s < 2; ++s) {
      U4 bf;
#pragma unroll
      for (int q = 0; q < 4; ++q) {
        int vA = (q < 2) ? o2[4 * s + (q & 1)]     : p2[4 * s + (q & 1)];
        int vB = (q < 2) ? p2[4 * s + 2 + (q & 1)] : o2[4 * s + 2 + (q & 1)];
        bf.u[q] = hi ? (u32)vB : (u32)vA;
      }
      c3 = MFMA(A3[s], bf.h, c3);
    }

    // ---- epilogue: out[px][ch] = x + (dx + b3)*mask -----------------------
    const int px = blockIdx.x * 256 + wid * 64 + lpx;
    bool ms;
    if (mw == 1)      ms = ((const u8*)maskv)[px] != 0;
    else if (mw == 2) ms = ((const u16*)maskv)[px] != 0;
    else              ms = ((const u32*)maskv)[px] != 0;
    const float mf = ms ? 1.0f : 0.0f;
#pragma unroll
    for (int half = 0; half < 2; ++half) {
      const int ch0 = half ? (8 + 4 * hi) : (4 * hi);
      const float4 bv = half ? b3b : b3a;
      float d0 = c3[half * 4 + 0] + bv.x;
      float d1 = c3[half * 4 + 1] + bv.y;
      float d2 = c3[half * 4 + 2] + bv.z;
      float d3 = c3[half * 4 + 3] + bv.w;
      const int e = px * 16 + ch0;
      if (BF16) {
        ushort4 xu = *(const ushort4*)((const u16*)xv + e);
        float o0 = fmaf(d0, mf, bf2f(xu.x));
        float o1v = fmaf(d1, mf, bf2f(xu.y));
        float o2v = fmaf(d2, mf, bf2f(xu.z));
        float o3v = fmaf(d3, mf, bf2f(xu.w));
        uint2 w; w.x = pkbf(o0, o1v); w.y = pkbf(o2v, o3v);
        *(uint2*)((u16*)outv + e) = w;
      } else {
        float4 xc = *(const float4*)((const float*)xv + e);
        float4 o;
        o.x = fmaf(d0, mf, xc.x); o.y = fmaf(d1, mf, xc.y);
        o.z = fmaf(d2, mf, xc.z); o.w = fmaf(d3, mf, xc.w);
        *(float4*)((float*)outv + e) = o;
      }
    }
  }
}

__global__ __launch_bounds__(256) void nca_main(const void* __restrict__ xv,
                                                const u8* __restrict__ Wb,
                                                const void* __restrict__ maskv,
                                                const u32* __restrict__ flags,
                                                void* __restrict__ outv) {
  __shared__ __align__(16) u8 smem[4 * 9216];
  const bool isbf = flags[0] != 0;   // wave-uniform
  const int mw = (int)flags[1];
  if (isbf) nca_body<true>(xv, Wb, maskv, mw, outv, smem);
  else      nca_body<false>(xv, Wb, maskv, mw, outv, smem);
}

// ---------------------------------------------------------------------------
extern "C" void kernel_launch(void* const* d_in, const int* in_sizes, int n_in,
                              void* d_out, int out_size, void* d_ws, size_t ws_size,
                              hipStream_t stream) {
  // d_in: 0=x, 1=w1, 2=b1, 3=w2, 4=b2, 5=w3, 6=b3, 7=update_mask
  u32* flags = (u32*)d_ws;
  u8* Wb = (u8*)d_ws + 64;

  probe_kernel<<<1, 256, 0, stream>>>((const u16*)d_in[1], (const u32*)d_in[7], flags);

  prep_weights<<<(PREP_N + 255) / 256, 256, 0, stream>>>(
      d_in[1], d_in[2], d_in[3], d_in[4], d_in[5], d_in[6], flags, Wb);

  const int pixels = in_sizes[7];            // B*H*W = 1048576
  const int blocks = pixels / 256;           // 4096: one 256-px row per block
  nca_main<<<blocks, 256, 0, stream>>>(d_in[0], Wb, d_in[7], flags, d_out);
}

// Round 3
// 223.776 us; speedup vs baseline: 5.9473x; 1.2098x over previous
//
#include <hip/hip_runtime.h>
#include <hip/hip_bf16.h>

typedef unsigned int u32;
typedef unsigned short u16;
typedef unsigned char u8;

typedef float f32x16 __attribute__((ext_vector_type(16)));
typedef short bf16x8 __attribute__((ext_vector_type(8)));

// ---- workspace layout (bytes after 64B flag header) ------------------------
// A1eff[9 off][2 mt][2 hi][32 lane][8 k] bf16   (stencil folded into W1^T) 18432B
// A1b  [2 mt][2 hi][32 lane][8 k]       bf16   (b1/16 replicated)          2048B
// WT2p [32 ch][80 k]                    bf16   (k64 = b2, rest 0-pad)      5120B
// WT3p [32 ch][32 k]                    bf16   (ch 16..31 = 0)             2048B
// B3   [16]                             f32                                  64B
#define OFF_A1  0
#define OFF_A1B 18432
#define OFF_WT2 20480
#define OFF_WT3 25600
#define OFF_B3  27648
#define PREP_N  13840   // 9216 + 1024 + 2560 + 1024 + 16

// ---------------------------------------------------------------------------
// Probe (verified R1/R2): flags[0]=1 if float inputs are bf16,
// flags[1] = mask element width in bytes (1/2/4).
// ---------------------------------------------------------------------------
__global__ void probe_kernel(const u16* __restrict__ w1h,
                             const u32* __restrict__ maskw,
                             u32* __restrict__ flags) {
  __shared__ int sg, su8, sbf;
  if (threadIdx.x == 0) { sg = 0; su8 = 0; sbf = 0; }
  __syncthreads();
  int g = 0;
#pragma unroll
  for (int i = 0; i < 8; ++i) {
    u16 h = w1h[threadIdx.x * 8 + i];
    int e = (h >> 7) & 0xFF;
    if (e >= 0xC0) g++;
  }
  if (g) atomicAdd(&sg, g);
  u32 w = maskw[threadIdx.x];
  bool bytes01 = ((w & 0xFEFEFEFEu) == 0u);
  int bsum = (int)(w & 1u) + (int)((w >> 8) & 1u) +
             (int)((w >> 16) & 1u) + (int)((w >> 24) & 1u);
  if (bytes01 && bsum >= 2) atomicAdd(&su8, 1);
  if (w == 0x3F803F80u || w == 0x00003F80u) atomicAdd(&sbf, 1);
  __syncthreads();
  if (threadIdx.x == 0) {
    flags[0] = (sg == 0) ? 1u : 0u;
    flags[1] = (su8 > 0) ? 1u : ((sbf > 0) ? 2u : 4u);
  }
}

__device__ __forceinline__ float bf2f(u16 h) {
  return __uint_as_float(((u32)h) << 16);
}
__device__ __forceinline__ u16 f2bf(float f) {  // RNE (prep only, not hot)
  u32 u = __float_as_uint(f);
  return (u16)((u + 0x7FFFu + ((u >> 16) & 1u)) >> 16);
}
// hot-path pack: round-half-up + byte-perm (3 VALU ops vs ~10 for RNE pair)
__device__ __forceinline__ u32 pkbf(float a, float b) {
  u32 ua = __float_as_uint(a) + 0x8000u;
  u32 ub = __float_as_uint(b) + 0x8000u;
  return __builtin_amdgcn_perm(ub, ua, 0x07060302);  // {b.hi16, a.hi16}
}
__device__ __forceinline__ float rdv(const void* s, int i, bool bf) {
  return bf ? bf2f(((const u16*)s)[i]) : ((const float*)s)[i];
}

// ---------------------------------------------------------------------------
// Weight prep: fold perceive stencil into W1 (A1eff), build bias frag,
// transposed K-augmented W2, padded W3, f32 b3.
// ---------------------------------------------------------------------------
__global__ void prep_weights(const void* __restrict__ w1, const void* __restrict__ b1,
                             const void* __restrict__ w2, const void* __restrict__ b2,
                             const void* __restrict__ w3, const void* __restrict__ b3,
                             const u32* __restrict__ flags, u8* __restrict__ Wb) {
  int i = blockIdx.x * 256 + threadIdx.x;
  if (i >= PREP_N) return;
  const bool bf = flags[0] != 0;
  if (i < 9216) {                       // A1eff
    int off = i >> 10, rem = i & 1023;
    int mt = rem >> 9, hi = (rem >> 8) & 1, l = (rem >> 3) & 31, k8 = i & 7;
    int ch = mt * 32 + l, k = hi * 8 + k8;
    int oi = off / 3, oj = off % 3;
    const float axv[3] = {1.f, 2.f, 1.f};
    const float bxv[3] = {-1.f, 0.f, 1.f};
    float ci  = (oi == 1 && oj == 1) ? 1.f : 0.f;
    float dxv = axv[oi] * bxv[oj] * 0.125f;   // sobel-x coef at (oi,oj)
    float dyv = axv[oj] * bxv[oi] * 0.125f;   // sobel-y = transpose
    float v = ci  * rdv(w1, (3 * k + 0) * 64 + ch, bf)
            + dxv * rdv(w1, (3 * k + 1) * 64 + ch, bf)
            + dyv * rdv(w1, (3 * k + 2) * 64 + ch, bf);
    ((u16*)(Wb + OFF_A1))[i] = f2bf(v);
  } else if (i < 10240) {               // A1b: b1/16 in every k slot
    int j = i - 9216;
    int mt = j >> 9, l = (j >> 3) & 31;
    ((u16*)(Wb + OFF_A1B))[j] = f2bf(rdv(b1, mt * 32 + l, bf) * 0.0625f);
  } else if (i < 12800) {               // WT2p: j = n*80 + k
    int j = i - 10240, n = j / 80, k = j - n * 80;
    float v = (k < 64) ? rdv(w2, k * 32 + n, bf)
                       : ((k == 64) ? rdv(b2, n, bf) : 0.0f);
    ((u16*)(Wb + OFF_WT2))[j] = f2bf(v);
  } else if (i < 13824) {               // WT3p: j = n*32 + k
    int j = i - 12800, n = j >> 5, k = j & 31;
    float v = (n < 16) ? rdv(w3, k * 16 + n, bf) : 0.0f;
    ((u16*)(Wb + OFF_WT3))[j] = f2bf(v);
  } else {                              // B3 f32
    int j = i - 13824;
    ((float*)(Wb + OFF_B3))[j] = rdv(b3, j, bf);
  }
}

// ---------------------------------------------------------------------------
// Main kernel
// ---------------------------------------------------------------------------
__device__ __forceinline__ float fast_tanh(float x) {
  float e = __expf(2.0f * x);
  float r = __builtin_amdgcn_rcpf(e + 1.0f);
  return fmaf(-2.0f, r, 1.0f);
}

union U4 { uint4 q; u32 u[4]; bf16x8 h; };

#define MFMA(a, b, c) __builtin_amdgcn_mfma_f32_32x32x16_bf16((a), (b), (c), 0, 0, 0)

// LDS x tile: xs[3 rows][258 cols][16 ch] bf16, row stride 8256 B.
// col index = image col + 1 (halo cols 0 and 257 are zero).
template <bool BF16>
__device__ __forceinline__ void nca_body(const void* __restrict__ xv,
                                         const u8* __restrict__ Wb,
                                         const void* __restrict__ maskv, int mw,
                                         void* __restrict__ outv,
                                         u8* __restrict__ xs) {
  const int tid = threadIdx.x;
  const int l   = tid & 63;
  const int wid = tid >> 6;
  const int l31 = l & 31;
  const int hi  = l >> 5;
  const int hpos = blockIdx.x & 255;
  const int img  = blockIdx.x >> 8;

  // ---- stage x rows h-1,h,h+1 into LDS as bf16 (zero halo) ----------------
  if (tid < 6) {
    int r = tid >> 1, b = tid & 1;
    uint4 z = make_uint4(0, 0, 0, 0);
    uint4* d = (uint4*)(xs + r * 8256 + (b ? 257 : 0) * 32);
    d[0] = z; d[1] = z;
  }
#pragma unroll
  for (int r = 0; r < 3; ++r) {
    int hr = hpos - 1 + r;
    bool valid = (hr >= 0) && (hr <= 255);
    if (BF16) {
      const u16* src = (const u16*)xv + ((size_t)(img * 256 + hr) << 12);
#pragma unroll
      for (int s = 0; s < 2; ++s) {
        int c = s * 256 + tid;        // 16B chunk: col c>>1, half c&1
        uint4 v = make_uint4(0, 0, 0, 0);
        if (valid) v = *(const uint4*)(src + c * 8);
        *(uint4*)(xs + r * 8256 + ((c >> 1) + 1) * 32 + (c & 1) * 16) = v;
      }
    } else {
      const float* src = (const float*)xv + ((size_t)(img * 256 + hr) << 12);
#pragma unroll
      for (int k = 0; k < 4; ++k) {
        int q = k * 256 + tid;        // float4 #q: col q>>2, ch-quad q&3
        uint2 w = make_uint2(0, 0);
        if (valid) {
          float4 v = *(const float4*)(src + q * 4);
          w.x = pkbf(v.x, v.y); w.y = pkbf(v.z, v.w);
        }
        *(uint2*)(xs + r * 8256 + ((q >> 2) + 1) * 32 + (q & 3) * 8) = w;
      }
    }
  }
  __syncthreads();

  // ---- bias A-frags (persist across both tiles) ---------------------------
  bf16x8 A1b[2];
#pragma unroll
  for (int mt = 0; mt < 2; ++mt) {
    U4 t; t.q = *(const uint4*)(Wb + OFF_A1B + ((mt * 2 + hi) * 32 + l31) * 16);
    A1b[mt] = t.h;
  }
  U4 ones; ones.u[0] = ones.u[1] = ones.u[2] = ones.u[3] = 0x3F803F80u;

  // ---- per 32-pixel tile ---------------------------------------------------
#pragma unroll
  for (int pt = 0; pt < 2; ++pt) {
    const int cb  = wid * 64 + pt * 32;   // tile base image col
    const int lpx = cb + l31;             // this lane's C-column pixel (col)

    // ---- layer 1: 1 bias MFMA + 9 shifted-offset MFMAs per M-tile ---------
    f32x16 c0 = {0,0,0,0,0,0,0,0,0,0,0,0,0,0,0,0};
    f32x16 c1 = {0,0,0,0,0,0,0,0,0,0,0,0,0,0,0,0};
    c0 = MFMA(A1b[0], ones.h, c0);
    c1 = MFMA(A1b[1], ones.h, c1);
#pragma unroll
    for (int off = 0; off < 9; ++off) {
      const int oi = off / 3, oj = off % 3;
      U4 bx; bx.q = *(const uint4*)(xs + oi * 8256 + (cb + l31 + oj) * 32 + hi * 16);
      U4 a0; a0.q = *(const uint4*)(Wb + OFF_A1 + (((off * 2 + 0) * 2 + hi) * 32 + l31) * 16);
      U4 a1; a1.q = *(const uint4*)(Wb + OFF_A1 + (((off * 2 + 1) * 2 + hi) * 32 + l31) * 16);
      c0 = MFMA(a0.h, bx.h, c0);
      c1 = MFMA(a1.h, bx.h, c1);
    }

    // tanh + pack pairs: o1[mt*8 + g*2 + pp] = ch (32mt+8g+4hi+2pp, +1)
    int o1[16];
#pragma unroll
    for (int g = 0; g < 4; ++g)
#pragma unroll
      for (int pp = 0; pp < 2; ++pp) {
        o1[g * 2 + pp]     = pkbf(fast_tanh(c0[g * 4 + 2 * pp]), fast_tanh(c0[g * 4 + 2 * pp + 1]));
        o1[8 + g * 2 + pp] = pkbf(fast_tanh(c1[g * 4 + 2 * pp]), fast_tanh(c1[g * 4 + 2 * pp + 1]));
      }
    int p1[16];
#pragma unroll
    for (int i = 0; i < 16; ++i) p1[i] = __shfl_xor(o1[i], 32, 64);

    // ---- layer 2: 5 K-steps (last = bias row), A2 from L1-hot global ------
    f32x16 c2 = {0,0,0,0,0,0,0,0,0,0,0,0,0,0,0,0};
#pragma unroll
    for (int s = 0; s < 4; ++s) {
      U4 a2; a2.q = *(const uint4*)(Wb + OFF_WT2 + l31 * 160 + s * 32 + hi * 16);
      U4 bf;
      const int mt8 = (s >> 1) * 8;
      const int g0 = ((2 * s) & 3) * 2, g1 = ((2 * s + 1) & 3) * 2;
#pragma unroll
      for (int q = 0; q < 4; ++q) {
        int vA = (q < 2) ? o1[mt8 + g0 + (q & 1)] : p1[mt8 + g0 + (q & 1)];
        int vB = (q < 2) ? p1[mt8 + g1 + (q & 1)] : o1[mt8 + g1 + (q & 1)];
        bf.u[q] = hi ? (u32)vB : (u32)vA;
      }
      c2 = MFMA(a2.h, bf.h, c2);
    }
    {
      U4 a2; a2.q = *(const uint4*)(Wb + OFF_WT2 + l31 * 160 + 4 * 32 + hi * 16);
      U4 bb; bb.u[0] = hi ? 0u : 0x00003F80u; bb.u[1] = 0; bb.u[2] = 0; bb.u[3] = 0;
      c2 = MFMA(a2.h, bb.h, c2);
    }
    int o2[8];
#pragma unroll
    for (int g = 0; g < 4; ++g)
#pragma unroll
      for (int pp = 0; pp < 2; ++pp)
        o2[g * 2 + pp] = pkbf(fast_tanh(c2[g * 4 + 2 * pp]), fast_tanh(c2[g * 4 + 2 * pp + 1]));
    int p2[8];
#pragma unroll
    for (int i = 0; i < 8; ++i) p2[i] = __shfl_xor(o2[i], 32, 64);

    // ---- layer 3: 2 K-steps (ch 0..15 valid) ------------------------------
    f32x16 c3 = {0,0,0,0,0,0,0,0,0,0,0,0,0,0,0,0};
#pragma unroll
    for (int s = 0; s < 2; ++s) {
      U4 a3; a3.q = *(const uint4*)(Wb + OFF_WT3 + l31 * 64 + s * 32 + hi * 16);
      U4 bf;
#pragma unroll
      for (int q = 0; q < 4; ++q) {
        int vA = (q < 2) ? o2[4 * s + (q & 1)]     : p2[4 * s + (q & 1)];
        int vB = (q < 2) ? p2[4 * s + 2 + (q & 1)] : o2[4 * s + 2 + (q & 1)];
        bf.u[q] = hi ? (u32)vB : (u32)vA;
      }
      c3 = MFMA(a3.h, bf.h, c3);
    }

    // ---- epilogue: out[px][ch] = x + (dx + b3)*mask -----------------------
    const float* B3f = (const float*)(Wb + OFF_B3);
    float4 b3a = *(const float4*)(B3f + 4 * hi);
    float4 b3b = *(const float4*)(B3f + 8 + 4 * hi);
    const int px = blockIdx.x * 256 + lpx;
    bool ms;
    if (mw == 1)      ms = ((const u8*)maskv)[px] != 0;
    else if (mw == 2) ms = ((const u16*)maskv)[px] != 0;
    else              ms = ((const u32*)maskv)[px] != 0;
    const float mf = ms ? 1.0f : 0.0f;
#pragma unroll
    for (int half = 0; half < 2; ++half) {
      const int ch0 = half ? (8 + 4 * hi) : (4 * hi);
      const float4 bv = half ? b3b : b3a;
      float d0 = c3[half * 4 + 0] + bv.x;
      float d1 = c3[half * 4 + 1] + bv.y;
      float d2 = c3[half * 4 + 2] + bv.z;
      float d3 = c3[half * 4 + 3] + bv.w;
      const int e = px * 16 + ch0;
      if (BF16) {
        ushort4 xu = *(const ushort4*)((const u16*)xv + e);
        float o0 = fmaf(d0, mf, bf2f(xu.x));
        float o1v = fmaf(d1, mf, bf2f(xu.y));
        float o2v = fmaf(d2, mf, bf2f(xu.z));
        float o3v = fmaf(d3, mf, bf2f(xu.w));
        uint2 w; w.x = pkbf(o0, o1v); w.y = pkbf(o2v, o3v);
        *(uint2*)((u16*)outv + e) = w;
      } else {
        float4 xc = *(const float4*)((const float*)xv + e);
        float4 o;
        o.x = fmaf(d0, mf, xc.x); o.y = fmaf(d1, mf, xc.y);
        o.z = fmaf(d2, mf, xc.z); o.w = fmaf(d3, mf, xc.w);
        *(float4*)((float*)outv + e) = o;
      }
    }
  }
}

__global__ __launch_bounds__(256, 4) void nca_main(const void* __restrict__ xv,
                                                   const u8* __restrict__ Wb,
                                                   const void* __restrict__ maskv,
                                                   const u32* __restrict__ flags,
                                                   void* __restrict__ outv) {
  __shared__ __align__(16) u8 smem[3 * 8256];
  const bool isbf = flags[0] != 0;   // wave-uniform
  const int mw = (int)flags[1];
  if (isbf) nca_body<true>(xv, Wb, maskv, mw, outv, smem);
  else      nca_body<false>(xv, Wb, maskv, mw, outv, smem);
}

// ---------------------------------------------------------------------------
extern "C" void kernel_launch(void* const* d_in, const int* in_sizes, int n_in,
                              void* d_out, int out_size, void* d_ws, size_t ws_size,
                              hipStream_t stream) {
  // d_in: 0=x, 1=w1, 2=b1, 3=w2, 4=b2, 5=w3, 6=b3, 7=update_mask
  u32* flags = (u32*)d_ws;
  u8* Wb = (u8*)d_ws + 64;

  probe_kernel<<<1, 256, 0, stream>>>((const u16*)d_in[1], (const u32*)d_in[7], flags);

  prep_weights<<<(PREP_N + 255) / 256, 256, 0, stream>>>(
      d_in[1], d_in[2], d_in[3], d_in[4], d_in[5], d_in[6], flags, Wb);

  const int pixels = in_sizes[7];            // B*H*W = 1048576
  const int blocks = pixels / 256;           // 4096: one 256-px image row per block
  nca_main<<<blocks, 256, 0, stream>>>(d_in[0], Wb, d_in[7], flags, d_out);
}

// Round 4
// 215.620 us; speedup vs baseline: 6.1723x; 1.0378x over previous
//
#include <hip/hip_runtime.h>
#include <hip/hip_bf16.h>

typedef unsigned int u32;
typedef unsigned short u16;
typedef unsigned char u8;

typedef float f32x16 __attribute__((ext_vector_type(16)));
typedef short bf16x8 __attribute__((ext_vector_type(8)));

// ---- workspace layout (bytes after 64B flag header) ------------------------
// A1eff[9 off][2 mt][2 hi][32 lane][8 k] bf16 (stencil folded into W1^T) 18432B
// A1b  [2 mt][2 hi][32 lane][8 k]       bf16 (b1/16 replicated)          2048B
// WT2p [32 ch][80 k]  bf16  K-PERMUTED to match o1 register order        5120B
// WT3p [32 row][32 k] bf16  K-permuted to o2 order, M-permuted so lane
//                           (n,hh) ends with ch 8hh..8hh+7 contiguous    2048B
// B3   [16] f32                                                            64B
#define OFF_A1  0
#define OFF_A1B 18432
#define OFF_WT2 20480
#define OFF_WT3 25600
#define OFF_B3  27648
#define PREP_N  13840   // 9216 + 1024 + 2560 + 1024 + 16

// ---------------------------------------------------------------------------
// Probe (verified R1-R3): flags[0]=1 if float inputs are bf16,
// flags[1] = mask element width in bytes (1/2/4).
// ---------------------------------------------------------------------------
__global__ void probe_kernel(const u16* __restrict__ w1h,
                             const u32* __restrict__ maskw,
                             u32* __restrict__ flags) {
  __shared__ int sg, su8, sbf;
  if (threadIdx.x == 0) { sg = 0; su8 = 0; sbf = 0; }
  __syncthreads();
  int g = 0;
#pragma unroll
  for (int i = 0; i < 8; ++i) {
    u16 h = w1h[threadIdx.x * 8 + i];
    int e = (h >> 7) & 0xFF;
    if (e >= 0xC0) g++;
  }
  if (g) atomicAdd(&sg, g);
  u32 w = maskw[threadIdx.x];
  bool bytes01 = ((w & 0xFEFEFEFEu) == 0u);
  int bsum = (int)(w & 1u) + (int)((w >> 8) & 1u) +
             (int)((w >> 16) & 1u) + (int)((w >> 24) & 1u);
  if (bytes01 && bsum >= 2) atomicAdd(&su8, 1);
  if (w == 0x3F803F80u || w == 0x00003F80u) atomicAdd(&sbf, 1);
  __syncthreads();
  if (threadIdx.x == 0) {
    flags[0] = (sg == 0) ? 1u : 0u;
    flags[1] = (su8 > 0) ? 1u : ((sbf > 0) ? 2u : 4u);
  }
}

__device__ __forceinline__ float bf2f(u16 h) {
  return __uint_as_float(((u32)h) << 16);
}
__device__ __forceinline__ u16 f2bf(float f) {  // RNE (prep only)
  u32 u = __float_as_uint(f);
  return (u16)((u + 0x7FFFu + ((u >> 16) & 1u)) >> 16);
}
// hot-path pack: round-half-up + byte-perm (3 VALU ops)
__device__ __forceinline__ u32 pkbf(float a, float b) {
  u32 ua = __float_as_uint(a) + 0x8000u;
  u32 ub = __float_as_uint(b) + 0x8000u;
  return __builtin_amdgcn_perm(ub, ua, 0x07060302);  // {b.hi16, a.hi16}
}
__device__ __forceinline__ float rdv(const void* s, int i, bool bf) {
  return bf ? bf2f(((const u16*)s)[i]) : ((const float*)s)[i];
}

// ---------------------------------------------------------------------------
// Weight prep.
// K-permutation (layers 2,3): logical k-slot = 16s + 8hh + 2q + e must hold
// the channel resident in o{1,2}[4s+q] bf16-half e of a hh-half lane:
//   L2: c = 32*(s>>1) + 8*(2*(s&1)+(q>>1)) + 4*hh + 2*(q&1) + e
//   L3: c = 8*(2*s+(q>>1)) + 4*hh + 2*(q&1) + e
// M-permutation (layer 3): row r<16 holds output channel
//   cout(r) = (r&3) + 4*((r>>3)&1) + 8*((r>>2)&1)   (rows 16..31 zero)
// so lane (n,hh) reg e (e<8) = channel 8hh+e  -> contiguous 32B per lane.
// ---------------------------------------------------------------------------
__global__ void prep_weights(const void* __restrict__ w1, const void* __restrict__ b1,
                             const void* __restrict__ w2, const void* __restrict__ b2,
                             const void* __restrict__ w3, const void* __restrict__ b3,
                             const u32* __restrict__ flags, u8* __restrict__ Wb) {
  int i = blockIdx.x * 256 + threadIdx.x;
  if (i >= PREP_N) return;
  const bool bf = flags[0] != 0;
  if (i < 9216) {                       // A1eff (verified R3)
    int off = i >> 10, rem = i & 1023;
    int mt = rem >> 9, hi = (rem >> 8) & 1, l = (rem >> 3) & 31, k8 = i & 7;
    int ch = mt * 32 + l, k = hi * 8 + k8;
    int oi = off / 3, oj = off % 3;
    const float axv[3] = {1.f, 2.f, 1.f};
    const float bxv[3] = {-1.f, 0.f, 1.f};
    float ci  = (oi == 1 && oj == 1) ? 1.f : 0.f;
    float dxv = axv[oi] * bxv[oj] * 0.125f;
    float dyv = axv[oj] * bxv[oi] * 0.125f;
    float v = ci  * rdv(w1, (3 * k + 0) * 64 + ch, bf)
            + dxv * rdv(w1, (3 * k + 1) * 64 + ch, bf)
            + dyv * rdv(w1, (3 * k + 2) * 64 + ch, bf);
    ((u16*)(Wb + OFF_A1))[i] = f2bf(v);
  } else if (i < 10240) {               // A1b: b1/16 in every k slot
    int j = i - 9216;
    int mt = j >> 9, l = (j >> 3) & 31;
    ((u16*)(Wb + OFF_A1B))[j] = f2bf(rdv(b1, mt * 32 + l, bf) * 0.0625f);
  } else if (i < 12800) {               // WT2p (K-permuted)
    int j = i - 10240, n = j / 80, k = j - n * 80;
    float v;
    if (k < 64) {
      int s = k >> 4, hh = (k >> 3) & 1, q = (k & 7) >> 1, e = k & 1;
      int c = 32 * (s >> 1) + 8 * (2 * (s & 1) + (q >> 1)) + 4 * hh + 2 * (q & 1) + e;
      v = rdv(w2, c * 32 + n, bf);
    } else {
      v = (k == 64) ? rdv(b2, n, bf) : 0.0f;
    }
    ((u16*)(Wb + OFF_WT2))[j] = f2bf(v);
  } else if (i < 13824) {               // WT3p (K- and M-permuted)
    int j = i - 12800, n = j >> 5, k = j & 31;
    float v = 0.0f;
    if (n < 16) {
      int cout = (n & 3) + 4 * ((n >> 3) & 1) + 8 * ((n >> 2) & 1);
      int s = k >> 4, hh = (k >> 3) & 1, q = (k & 7) >> 1, e = k & 1;
      int cin = 8 * (2 * s + (q >> 1)) + 4 * hh + 2 * (q & 1) + e;
      v = rdv(w3, cin * 16 + cout, bf);
    }
    ((u16*)(Wb + OFF_WT3))[j] = f2bf(v);
  } else {                              // B3 f32
    int j = i - 13824;
    ((float*)(Wb + OFF_B3))[j] = rdv(b3, j, bf);
  }
}

// ---------------------------------------------------------------------------
// Main kernel
// ---------------------------------------------------------------------------
__device__ __forceinline__ float fast_tanh(float x) {
  float e = __expf(2.0f * x);
  float r = __builtin_amdgcn_rcpf(e + 1.0f);
  return fmaf(-2.0f, r, 1.0f);
}

union U4 { uint4 q; u32 u[4]; bf16x8 h; float4 f; };

__device__ __forceinline__ void wave_lds_fence() {
  __builtin_amdgcn_wave_barrier();
  __asm__ __volatile__("s_waitcnt lgkmcnt(0)" ::: "memory");
  __builtin_amdgcn_wave_barrier();
}

#define MFMA(a, b, c) __builtin_amdgcn_mfma_f32_32x32x16_bf16((a), (b), (c), 0, 0, 0)

// LDS: xs[4 rows][258 cols][16 ch bf16] (stride 8256B, halo cols 0/257 zero)
//    + scratch[4 waves][64 px][80B]  (stride-80 pad, dx transpose)
#define XS_STRIDE 8256
#define SCR_OFF   33024
#define SCR_WAVE  5120
#define LDS_TOTAL 53504

template <bool BF16>
__device__ __forceinline__ void nca_body(const void* __restrict__ xv,
                                         const u8* __restrict__ Wb,
                                         const void* __restrict__ maskv, int mw,
                                         void* __restrict__ outv,
                                         u8* __restrict__ xs) {
  const int tid = threadIdx.x;
  const int l   = tid & 63;
  const int wid = tid >> 6;
  const int l31 = l & 31;
  const int hi  = l >> 5;
  const int img   = blockIdx.x >> 7;
  const int r0    = (blockIdx.x & 127) << 1;      // first of 2 output rows

  // ---- stage x rows r0-1 .. r0+2 into LDS as bf16 (zero halo) -------------
  if (tid < 8) {        // halo cols 0 and 257, 4 rows
    int rr = tid >> 1, side = tid & 1;
    uint4 z = make_uint4(0, 0, 0, 0);
    uint4* d = (uint4*)(xs + rr * XS_STRIDE + (side ? 257 : 0) * 32);
    d[0] = z; d[1] = z;
  }
#pragma unroll
  for (int rr = 0; rr < 4; ++rr) {
    int hr = r0 - 1 + rr;
    bool valid = (hr >= 0) && (hr <= 255);
    if (BF16) {
      const u16* src = (const u16*)xv + ((size_t)(img * 256 + hr) << 12);
#pragma unroll
      for (int s = 0; s < 2; ++s) {
        int c = s * 256 + tid;        // 16B chunk: col c>>1, half c&1
        uint4 v = make_uint4(0, 0, 0, 0);
        if (valid) v = *(const uint4*)(src + c * 8);
        *(uint4*)(xs + rr * XS_STRIDE + ((c >> 1) + 1) * 32 + (c & 1) * 16) = v;
      }
    } else {
      const float* src = (const float*)xv + ((size_t)(img * 256 + hr) << 12);
#pragma unroll
      for (int k = 0; k < 4; ++k) {
        int q = k * 256 + tid;        // float4 #q: col q>>2, ch-quad q&3
        uint2 w = make_uint2(0, 0);
        if (valid) {
          float4 v = *(const float4*)(src + q * 4);
          w.x = pkbf(v.x, v.y); w.y = pkbf(v.z, v.w);
        }
        *(uint2*)(xs + rr * XS_STRIDE + ((q >> 2) + 1) * 32 + (q & 3) * 8) = w;
      }
    }
  }
  __syncthreads();

  const int sr      = wid >> 1;                 // wave's top staged row
  const int colbase = (wid & 1) * 128;          // wave's column half
  const int gr      = img * 256 + r0 + sr;      // global image row
  const int growpix = gr << 8;                  // pixel index of row start

  // ---- hoisted invariants -------------------------------------------------
  bf16x8 A1b[2];
#pragma unroll
  for (int mt = 0; mt < 2; ++mt) {
    U4 t; t.q = *(const uint4*)(Wb + OFF_A1B + ((mt * 2 + hi) * 32 + l31) * 16);
    A1b[mt] = t.h;
  }
  U4 ones; ones.u[0] = ones.u[1] = ones.u[2] = ones.u[3] = 0x3F803F80u;
  const float* B3f = (const float*)(Wb + OFF_B3);
  float4 b3lo = *(const float4*)(B3f + 8 * hi);       // ch 8hi+0..3
  float4 b3hi4 = *(const float4*)(B3f + 8 * hi + 4);  // ch 8hi+4..7
  u8* scr = xs + SCR_OFF + wid * SCR_WAVE;

  // ---- 2 tile-pairs of 2 tiles (32 px each) -------------------------------
#pragma unroll
  for (int tp = 0; tp < 2; ++tp) {
#pragma unroll
    for (int u = 0; u < 2; ++u) {
      const int cb = colbase + (tp * 2 + u) * 32;

      // ---- layer 1: 2 bias MFMA + 9 shifted-offset MFMAs per M-tile -------
      f32x16 c0 = {0,0,0,0,0,0,0,0,0,0,0,0,0,0,0,0};
      f32x16 c1 = {0,0,0,0,0,0,0,0,0,0,0,0,0,0,0,0};
      c0 = MFMA(A1b[0], ones.h, c0);
      c1 = MFMA(A1b[1], ones.h, c1);
#pragma unroll
      for (int off = 0; off < 9; ++off) {
        const int oi = off / 3, oj = off % 3;
        U4 bx; bx.q = *(const uint4*)(xs + (sr + oi) * XS_STRIDE +
                                      (cb + l31 + oj) * 32 + hi * 16);
        U4 a0; a0.q = *(const uint4*)(Wb + OFF_A1 + (((off * 2 + 0) * 2 + hi) * 32 + l31) * 16);
        U4 a1; a1.q = *(const uint4*)(Wb + OFF_A1 + (((off * 2 + 1) * 2 + hi) * 32 + l31) * 16);
        c0 = MFMA(a0.h, bx.h, c0);
        c1 = MFMA(a1.h, bx.h, c1);
      }

      // tanh + pack: o1[mt*8+g*2+pp] = ch(32mt+8g+4hi+2pp, +1)
      u32 o1[16];
#pragma unroll
      for (int g = 0; g < 4; ++g)
#pragma unroll
        for (int pp = 0; pp < 2; ++pp) {
          o1[g * 2 + pp]     = pkbf(fast_tanh(c0[g * 4 + 2 * pp]), fast_tanh(c0[g * 4 + 2 * pp + 1]));
          o1[8 + g * 2 + pp] = pkbf(fast_tanh(c1[g * 4 + 2 * pp]), fast_tanh(c1[g * 4 + 2 * pp + 1]));
        }

      // ---- layer 2: B-frag = o1[4s..4s+3] (K-permuted weights) ------------
      f32x16 c2 = {0,0,0,0,0,0,0,0,0,0,0,0,0,0,0,0};
#pragma unroll
      for (int s = 0; s < 4; ++s) {
        U4 a2; a2.q = *(const uint4*)(Wb + OFF_WT2 + l31 * 160 + s * 32 + hi * 16);
        U4 bfr; bfr.u[0] = o1[4*s]; bfr.u[1] = o1[4*s+1]; bfr.u[2] = o1[4*s+2]; bfr.u[3] = o1[4*s+3];
        c2 = MFMA(a2.h, bfr.h, c2);
      }
      {
        U4 a2; a2.q = *(const uint4*)(Wb + OFF_WT2 + l31 * 160 + 4 * 32 + hi * 16);
        U4 bb; bb.u[0] = hi ? 0u : 0x00003F80u; bb.u[1] = 0; bb.u[2] = 0; bb.u[3] = 0;
        c2 = MFMA(a2.h, bb.h, c2);
      }
      u32 o2[8];
#pragma unroll
      for (int g = 0; g < 4; ++g)
#pragma unroll
        for (int pp = 0; pp < 2; ++pp)
          o2[g * 2 + pp] = pkbf(fast_tanh(c2[g * 4 + 2 * pp]), fast_tanh(c2[g * 4 + 2 * pp + 1]));

      // ---- layer 3: B-frag = o2[4s..4s+3]; M-permuted -> lane has ch 8hi+e
      f32x16 c3 = {0,0,0,0,0,0,0,0,0,0,0,0,0,0,0,0};
#pragma unroll
      for (int s = 0; s < 2; ++s) {
        U4 a3; a3.q = *(const uint4*)(Wb + OFF_WT3 + l31 * 64 + s * 32 + hi * 16);
        U4 bfr; bfr.u[0] = o2[4*s]; bfr.u[1] = o2[4*s+1]; bfr.u[2] = o2[4*s+2]; bfr.u[3] = o2[4*s+3];
        c3 = MFMA(a3.h, bfr.h, c3);
      }

      // dx + b3 -> per-wave LDS scratch (transpose for coalesced epilogue)
      U4 w0, w1;
      w0.f.x = c3[0] + b3lo.x;  w0.f.y = c3[1] + b3lo.y;
      w0.f.z = c3[2] + b3lo.z;  w0.f.w = c3[3] + b3lo.w;
      w1.f.x = c3[4] + b3hi4.x; w1.f.y = c3[5] + b3hi4.y;
      w1.f.z = c3[6] + b3hi4.z; w1.f.w = c3[7] + b3hi4.w;
      u8* sa = scr + (u * 32 + l31) * 80 + hi * 32;
      *(float4*)(sa) = w0.f;
      *(float4*)(sa + 16) = w1.f;
    }
    wave_lds_fence();

    // ---- epilogue for 64 px: fully-coalesced x reads + out writes ---------
    const int cb2 = colbase + tp * 64;
#pragma unroll
    for (int P = 0; P < 4; ++P) {
      const int px_l = P * 16 + (l >> 2);       // 0..63
      const int qd   = l & 3;                   // channel quad
      float4 dx = *(const float4*)(scr + px_l * 80 + qd * 16);
      const int gpx = growpix + cb2 + px_l;
      bool ms;
      if (mw == 1)      ms = ((const u8*)maskv)[gpx] != 0;
      else if (mw == 2) ms = ((const u16*)maskv)[gpx] != 0;
      else              ms = ((const u32*)maskv)[gpx] != 0;
      const float mf = ms ? 1.0f : 0.0f;
      const int e = gpx * 16 + qd * 4;
      if (BF16) {
        uint2 xu = *(const uint2*)((const u16*)xv + e);
        float x0 = bf2f((u16)(xu.x & 0xFFFF)), x1 = bf2f((u16)(xu.x >> 16));
        float x2 = bf2f((u16)(xu.y & 0xFFFF)), x3 = bf2f((u16)(xu.y >> 16));
        float o0 = fmaf(dx.x, mf, x0), o1v = fmaf(dx.y, mf, x1);
        float o2v = fmaf(dx.z, mf, x2), o3v = fmaf(dx.w, mf, x3);
        uint2 w; w.x = pkbf(o0, o1v); w.y = pkbf(o2v, o3v);
        *(uint2*)((u16*)outv + e) = w;
      } else {
        float4 xc = *(const float4*)((const float*)xv + e);
        float4 o;
        o.x = fmaf(dx.x, mf, xc.x); o.y = fmaf(dx.y, mf, xc.y);
        o.z = fmaf(dx.z, mf, xc.z); o.w = fmaf(dx.w, mf, xc.w);
        *(float4*)((float*)outv + e) = o;
      }
    }
    wave_lds_fence();   // reads done before next pair's scratch writes
  }
}

__global__ __launch_bounds__(256, 3) void nca_main(const void* __restrict__ xv,
                                                   const u8* __restrict__ Wb,
                                                   const void* __restrict__ maskv,
                                                   const u32* __restrict__ flags,
                                                   void* __restrict__ outv) {
  __shared__ __align__(16) u8 smem[LDS_TOTAL];
  const bool isbf = flags[0] != 0;   // wave-uniform
  const int mw = (int)flags[1];
  if (isbf) nca_body<true>(xv, Wb, maskv, mw, outv, smem);
  else      nca_body<false>(xv, Wb, maskv, mw, outv, smem);
}

// ---------------------------------------------------------------------------
extern "C" void kernel_launch(void* const* d_in, const int* in_sizes, int n_in,
                              void* d_out, int out_size, void* d_ws, size_t ws_size,
                              hipStream_t stream) {
  // d_in: 0=x, 1=w1, 2=b1, 3=w2, 4=b2, 5=w3, 6=b3, 7=update_mask
  u32* flags = (u32*)d_ws;
  u8* Wb = (u8*)d_ws + 64;

  probe_kernel<<<1, 256, 0, stream>>>((const u16*)d_in[1], (const u32*)d_in[7], flags);

  prep_weights<<<(PREP_N + 255) / 256, 256, 0, stream>>>(
      d_in[1], d_in[2], d_in[3], d_in[4], d_in[5], d_in[6], flags, Wb);

  const int pixels = in_sizes[7];            // B*H*W = 1048576
  const int blocks = pixels / 512;           // 2048: two 256-px rows per block
  nca_main<<<blocks, 256, 0, stream>>>(d_in[0], Wb, d_in[7], flags, d_out);
}